// Round 3
// baseline (482.929 us; speedup 1.0000x reference)
//
#include <hip/hip_runtime.h>

#define NN 100000
#define CH 64

// ---- degree count: deg[dst] += 1 per edge ----
__global__ void k_deg(const int* __restrict__ dst, float* __restrict__ deg, int E) {
    int i = blockIdx.x * blockDim.x + threadIdx.x;
    if (i < E) atomicAdd(&deg[dst[i]], 1.0f);
}

// ---- dinv = rsqrt(deg + 1)  (+1 = self loop) ----
__global__ void k_dinv(const float* __restrict__ deg, float* __restrict__ dinv, int N) {
    int i = blockIdx.x * blockDim.x + threadIdx.x;
    if (i < N) dinv[i] = rsqrtf(deg[i] + 1.0f);
}

// ---- h = x @ W_gcn  (f32, K=64, Ncol=64) ----
__global__ __launch_bounds__(256) void k_gemm(const float* __restrict__ x,
                                              const float* __restrict__ W,
                                              float* __restrict__ h, int N) {
    __shared__ float Ws[64][64];   // 16 KB
    __shared__ float xs[32][64];   // 8 KB
    int t = threadIdx.x;
    for (int i = t; i < 64 * 64; i += 256) Ws[i >> 6][i & 63] = W[i];
    int r0 = blockIdx.x * 32;
    for (int i = t; i < 32 * 64; i += 256) {
        int r = i >> 6, c = i & 63;
        int gr = r0 + r;
        xs[r][c] = (gr < N) ? x[(size_t)gr * CH + c] : 0.0f;
    }
    __syncthreads();
    int tc = t & 63;      // output column (coalesced store)
    int tr = t >> 6;      // 0..3, 8 rows each
    float acc[8];
#pragma unroll
    for (int i = 0; i < 8; ++i) acc[i] = 0.0f;
    for (int k = 0; k < 64; ++k) {
        float wv = Ws[k][tc];            // conflict-free: consecutive lanes
#pragma unroll
        for (int i = 0; i < 8; ++i)
            acc[i] += xs[tr * 8 + i][k] * wv;  // wave-uniform addr: broadcast
    }
#pragma unroll
    for (int i = 0; i < 8; ++i) {
        int gr = r0 + tr * 8 + i;
        if (gr < N) h[(size_t)gr * CH + tc] = acc[i];
    }
}

// ---- edge scatter: agg[d] += h[s] * dinv[s]*dinv[d], one thread per (edge,ch) ----
__global__ void k_scatter(const int* __restrict__ src, const int* __restrict__ dst,
                          const float* __restrict__ h, const float* __restrict__ dinv,
                          float* __restrict__ agg, int E) {
    int i = blockIdx.x * blockDim.x + threadIdx.x;
    int total = E * CH;                 // 76.8M < 2^31
    if (i >= total) return;
    int e = i >> 6;
    int c = i & 63;
    int s = src[e], d = dst[e];
    float w = dinv[s] * dinv[d];        // wave-uniform per 64-lane group -> cached
    atomicAdd(&agg[d * CH + c], h[s * CH + c] * w);
}

// ---- fused epilogue: self-loop + bias + relu + residual + MLP 64->32->32->2 ----
__global__ __launch_bounds__(256) void k_final(
        const float* __restrict__ agg, const float* __restrict__ h,
        const float* __restrict__ dinv, const float* __restrict__ x,
        const float* __restrict__ bgcn,
        const float* __restrict__ W1, const float* __restrict__ b1,
        const float* __restrict__ W2, const float* __restrict__ b2,
        const float* __restrict__ W3, const float* __restrict__ b3,
        float* __restrict__ out, int N) {
    __shared__ float W1s[64 * 32], W2s[32 * 32], W3s[32 * 2];
    __shared__ float b1s[32], b2s[32], b3s[2], bg[64];
    int t = threadIdx.x;
    for (int i = t; i < 64 * 32; i += 256) W1s[i] = W1[i];
    for (int i = t; i < 32 * 32; i += 256) W2s[i] = W2[i];
    if (t < 64) { W3s[t] = W3[t]; bg[t] = bgcn[t]; }
    if (t < 32) { b1s[t] = b1[t]; b2s[t] = b2[t]; }
    if (t < 2) b3s[t] = b3[t];
    __syncthreads();
    int n = blockIdx.x * blockDim.x + t;
    if (n >= N) return;

    float di = dinv[n];
    float sl = di * di;                 // self-loop norm
    float h3[32];
#pragma unroll
    for (int j = 0; j < 32; ++j) h3[j] = b1s[j];

    const float4* a4 = (const float4*)(agg + (size_t)n * CH);
    const float4* g4 = (const float4*)(h   + (size_t)n * CH);
    const float4* x4 = (const float4*)(x   + (size_t)n * CH);
#pragma unroll 4
    for (int q = 0; q < 16; ++q) {
        float4 a = a4[q], gv = g4[q], xv = x4[q];
        float pre[4] = {a.x + gv.x * sl, a.y + gv.y * sl,
                        a.z + gv.z * sl, a.w + gv.w * sl};
        float xr[4] = {xv.x, xv.y, xv.z, xv.w};
#pragma unroll
        for (int u = 0; u < 4; ++u) {
            int k = q * 4 + u;
            float v = fmaxf(pre[u] + bg[k], 0.0f) + xr[u];  // relu + residual
#pragma unroll
            for (int j = 0; j < 32; ++j)
                h3[j] += v * W1s[k * 32 + j];               // LDS broadcast reads
        }
    }
    float h4[32];
#pragma unroll
    for (int j = 0; j < 32; ++j) h4[j] = b2s[j];
#pragma unroll
    for (int k = 0; k < 32; ++k) {
        float v = fmaxf(h3[k], 0.0f);
#pragma unroll
        for (int j = 0; j < 32; ++j)
            h4[j] += v * W2s[k * 32 + j];
    }
    float y0 = b3s[0], y1 = b3s[1];
#pragma unroll
    for (int k = 0; k < 32; ++k) {
        float v = fmaxf(h4[k], 0.0f);
        y0 += v * W3s[k * 2 + 0];
        y1 += v * W3s[k * 2 + 1];
    }
    out[(size_t)n * 2 + 0] = y0;
    out[(size_t)n * 2 + 1] = y1;
}

extern "C" void kernel_launch(void* const* d_in, const int* in_sizes, int n_in,
                              void* d_out, int out_size, void* d_ws, size_t ws_size,
                              hipStream_t stream) {
    const float* x  = (const float*)d_in[0];
    const int*   ei = (const int*)d_in[1];   // int per harness convention
    const float* Wg = (const float*)d_in[2];
    const float* bg = (const float*)d_in[3];
    const float* W1 = (const float*)d_in[4];
    const float* b1 = (const float*)d_in[5];
    const float* W2 = (const float*)d_in[6];
    const float* b2 = (const float*)d_in[7];
    const float* W3 = (const float*)d_in[8];
    const float* b3 = (const float*)d_in[9];
    float* out = (float*)d_out;

    const int N = NN;
    const int E = in_sizes[1] / 2;
    const int* src = ei;
    const int* dst = ei + E;

    // ws layout: [deg N][agg 64N][dinv N][h 64N]  -> 130N floats = 52 MB
    float* ws   = (float*)d_ws;
    float* deg  = ws;
    float* agg  = ws + N;
    float* dinv = agg + (size_t)N * CH;
    float* h    = dinv + N;

    // zero deg+agg in one shot (adjacent)
    hipMemsetAsync(deg, 0, (size_t)(N + (size_t)N * CH) * sizeof(float), stream);

    k_deg<<<(E + 255) / 256, 256, 0, stream>>>(dst, deg, E);
    k_dinv<<<(N + 255) / 256, 256, 0, stream>>>(deg, dinv, N);
    k_gemm<<<(N + 31) / 32, 256, 0, stream>>>(x, Wg, h, N);
    int tot = E * CH;
    k_scatter<<<(tot + 255) / 256, 256, 0, stream>>>(src, dst, h, dinv, agg, E);
    k_final<<<(N + 255) / 256, 256, 0, stream>>>(agg, h, dinv, x, bg,
                                                 W1, b1, W2, b2, W3, b3, out, N);
}